// Round 5
// baseline (499.544 us; speedup 1.0000x reference)
//
#include <hip/hip_runtime.h>
#include <hip/hip_fp16.h>
#include <math.h>

#define NPTS 100000
#define CDIM 64
#define KNN  16

typedef unsigned int uint;

// DPP butterfly add: lane gets x + x[lane^mask]; CTRL is an immediate.
template <int CTRL>
__device__ __forceinline__ float dpp_add(float x) {
    int yi = __builtin_amdgcn_mov_dpp(__float_as_int(x), CTRL, 0xF, 0xF, true);
    return x + __int_as_float(yi);
}

// Blocked layouts (quarter-split channels): buf[quarter][n][16], quarter=c>>4.
// Channel c of point n lives at (c>>4)*NPTS*16 + n*16 + (c&15).

// ---------------------------------------------------------------------------
// Kernel A: fused q/k/v projection.  Thread = (row, col-quarter): computes 16
// output cols of q, k, v for one row.  Block 256 = 64 rows x 4 quarters (each
// wave is one quarter -> W addresses stay wave-uniform -> s_load).  4x waves
// and 1/4 per-wave scalar traffic vs 1-thread-per-full-row.  Stores are 64B
// contiguous per lane in the quarter-blocked layout.  k,v packed f16 pairs.
// ---------------------------------------------------------------------------
__global__ __launch_bounds__(256, 4) void proj_qkv(
    const float* __restrict__ feats,
    const float* __restrict__ Wq, const float* __restrict__ Wk,
    const float* __restrict__ Wv,
    float* __restrict__ qb, uint* __restrict__ kvb)
{
    const int t = threadIdx.x;
    const int quarter = t >> 6;            // wave-uniform
    const int c0 = quarter * 16;
    const long row = (long)blockIdx.x * 64 + (t & 63);
    const bool valid = row < NPTS;
    const long lrow = valid ? row : (NPTS - 1);

    float f[64];
    {
        const float4* fr = (const float4*)(feats + lrow * 64);
        #pragma unroll
        for (int i = 0; i < 16; ++i) {
            float4 x = fr[i];
            f[4*i+0] = x.x; f[4*i+1] = x.y; f[4*i+2] = x.z; f[4*i+3] = x.w;
        }
    }

    float acc[16];
    uint kb[8];

    // ---- q ----
    #pragma unroll
    for (int i = 0; i < 16; ++i) acc[i] = 0.f;
    #pragma unroll 1
    for (int jo = 0; jo < 8; ++jo) {
        #pragma unroll
        for (int ji = 0; ji < 8; ++ji) {
            const int j = jo * 8 + ji;
            const float fj = f[j];
            const float4* wr = (const float4*)(Wq + (size_t)j * 64 + c0);
            #pragma unroll
            for (int c4 = 0; c4 < 4; ++c4) {
                const float4 w = wr[c4];             // uniform -> s_load
                acc[4*c4+0] += fj * w.x; acc[4*c4+1] += fj * w.y;
                acc[4*c4+2] += fj * w.z; acc[4*c4+3] += fj * w.w;
            }
        }
    }
    if (valid) {
        float4* orow = (float4*)(qb + ((size_t)quarter * NPTS + row) * 16);
        #pragma unroll
        for (int i = 0; i < 4; ++i)
            orow[i] = make_float4(acc[4*i], acc[4*i+1], acc[4*i+2], acc[4*i+3]);
    }

    // ---- k ----
    #pragma unroll
    for (int i = 0; i < 16; ++i) acc[i] = 0.f;
    #pragma unroll 1
    for (int jo = 0; jo < 8; ++jo) {
        #pragma unroll
        for (int ji = 0; ji < 8; ++ji) {
            const int j = jo * 8 + ji;
            const float fj = f[j];
            const float4* wr = (const float4*)(Wk + (size_t)j * 64 + c0);
            #pragma unroll
            for (int c4 = 0; c4 < 4; ++c4) {
                const float4 w = wr[c4];
                acc[4*c4+0] += fj * w.x; acc[4*c4+1] += fj * w.y;
                acc[4*c4+2] += fj * w.z; acc[4*c4+3] += fj * w.w;
            }
        }
    }
    #pragma unroll
    for (int i = 0; i < 8; ++i) {
        const uint h0 = __half_as_ushort(__float2half(acc[2*i]));
        const uint h1 = __half_as_ushort(__float2half(acc[2*i+1]));
        kb[i] = h0 | (h1 << 16);
    }

    // ---- v + store packed kv ----
    #pragma unroll
    for (int i = 0; i < 16; ++i) acc[i] = 0.f;
    #pragma unroll 1
    for (int jo = 0; jo < 8; ++jo) {
        #pragma unroll
        for (int ji = 0; ji < 8; ++ji) {
            const int j = jo * 8 + ji;
            const float fj = f[j];
            const float4* wr = (const float4*)(Wv + (size_t)j * 64 + c0);
            #pragma unroll
            for (int c4 = 0; c4 < 4; ++c4) {
                const float4 w = wr[c4];
                acc[4*c4+0] += fj * w.x; acc[4*c4+1] += fj * w.y;
                acc[4*c4+2] += fj * w.z; acc[4*c4+3] += fj * w.w;
            }
        }
    }
    if (valid) {
        uint4* krow = (uint4*)(kvb + ((size_t)quarter * NPTS + row) * 16);
        #pragma unroll
        for (int i = 0; i < 4; ++i) {
            uint w[4];
            #pragma unroll
            for (int jj = 0; jj < 4; ++jj) {
                const int c = 4*i + jj;
                const uint kk = (c & 1) ? (kb[c >> 1] >> 16) : (kb[c >> 1] & 0xffffu);
                const uint vv = (uint)__half_as_ushort(__float2half(acc[c]));
                w[jj] = kk | (vv << 16);
            }
            krow[i] = make_uint4(w[0], w[1], w[2], w[3]);
        }
    }
}

// ---------------------------------------------------------------------------
// Kernel B: per-point kNN attention -> o_mid.  1 wave = 1 point, lane = c =
// h*8+d.  knn via readfirstlane -> s_load; one dword gather per neighbor
// (f16 k|v); dot over D=8 via DPP butterfly.  Zero DS-pipe ops.
// ---------------------------------------------------------------------------
__global__ __launch_bounds__(256) void attn_mid(
    const float* __restrict__ qb, const uint* __restrict__ kvb,
    const int* __restrict__ knn, float* __restrict__ ob)
{
    const int t = threadIdx.x;
    const int lane = t & 63;
    const int n = blockIdx.x * 4 + (t >> 6);
    const int ns = __builtin_amdgcn_readfirstlane(n);

    const size_t seg = (size_t)(lane >> 4) * ((size_t)NPTS * 16) + (lane & 15);

    const float qv = qb[seg + (size_t)n * 16];

    const int* kr = knn + (size_t)ns * KNN;
    int idx[KNN];
    #pragma unroll
    for (int i = 0; i < KNN; ++i) idx[i] = kr[i];   // uniform -> s_load

    float sc[KNN], vr[KNN];
    #pragma unroll
    for (int i = 0; i < KNN; ++i) {
        const uint w = kvb[seg + (size_t)idx[i] * 16];
        const float2 kvf = __half22float2(*(const __half2*)&w);
        vr[i] = kvf.y;
        float p = qv * kvf.x;
        p = dpp_add<0xB1>(p);    // quad_perm xor 1
        p = dpp_add<0x4E>(p);    // quad_perm xor 2
        p = dpp_add<0x141>(p);   // row_half_mirror == xor 7
        sc[i] = p * 0.3535533905932738f;   // 1/sqrt(8)
    }

    float m = sc[0];
    #pragma unroll
    for (int i = 1; i < KNN; ++i) m = fmaxf(m, sc[i]);
    float s = 0.f;
    #pragma unroll
    for (int i = 0; i < KNN; ++i) { sc[i] = __expf(sc[i] - m); s += sc[i]; }
    const float inv = 1.f / s;

    float acc = 0.f;
    #pragma unroll
    for (int i = 0; i < KNN; ++i) acc += sc[i] * vr[i];

    ob[seg + (size_t)n * 16] = acc * inv;
}

// ---------------------------------------------------------------------------
// Kernel C: out = o_mid @ Wo + bo.  Same col-split skeleton as kernel A.
// Reads blocked o_mid; writes standard row-major out.
// ---------------------------------------------------------------------------
__global__ __launch_bounds__(256, 4) void out_proj(
    const float* __restrict__ ob, const float* __restrict__ Wo,
    const float* __restrict__ bo, float* __restrict__ out)
{
    const int t = threadIdx.x;
    const int quarter = t >> 6;
    const int c0 = quarter * 16;
    const long row = (long)blockIdx.x * 64 + (t & 63);
    const bool valid = row < NPTS;
    const long lrow = valid ? row : (NPTS - 1);

    float f[64];
    #pragma unroll
    for (int qq = 0; qq < 4; ++qq) {
        const float4* fr = (const float4*)(ob + ((size_t)qq * NPTS + lrow) * 16);
        #pragma unroll
        for (int i = 0; i < 4; ++i) {
            float4 x = fr[i];
            f[qq*16 + 4*i+0] = x.x; f[qq*16 + 4*i+1] = x.y;
            f[qq*16 + 4*i+2] = x.z; f[qq*16 + 4*i+3] = x.w;
        }
    }

    float acc[16];
    {
        const float4* br = (const float4*)(bo + c0);
        #pragma unroll
        for (int i = 0; i < 4; ++i) {               // uniform -> s_load
            const float4 b = br[i];
            acc[4*i+0] = b.x; acc[4*i+1] = b.y; acc[4*i+2] = b.z; acc[4*i+3] = b.w;
        }
    }
    #pragma unroll 1
    for (int jo = 0; jo < 8; ++jo) {
        #pragma unroll
        for (int ji = 0; ji < 8; ++ji) {
            const int j = jo * 8 + ji;
            const float fj = f[j];
            const float4* wr = (const float4*)(Wo + (size_t)j * 64 + c0);
            #pragma unroll
            for (int c4 = 0; c4 < 4; ++c4) {
                const float4 w = wr[c4];
                acc[4*c4+0] += fj * w.x; acc[4*c4+1] += fj * w.y;
                acc[4*c4+2] += fj * w.z; acc[4*c4+3] += fj * w.w;
            }
        }
    }
    if (valid) {
        float4* orow = (float4*)(out + row * 64 + c0);
        #pragma unroll
        for (int i = 0; i < 4; ++i)
            orow[i] = make_float4(acc[4*i], acc[4*i+1], acc[4*i+2], acc[4*i+3]);
    }
}

extern "C" void kernel_launch(void* const* d_in, const int* in_sizes, int n_in,
                              void* d_out, int out_size, void* d_ws, size_t ws_size,
                              hipStream_t stream) {
    const float* feats = (const float*)d_in[0];
    const int*   knn   = (const int*)d_in[1];
    const float* Wq    = (const float*)d_in[2];
    const float* Wk    = (const float*)d_in[3];
    const float* Wv    = (const float*)d_in[4];
    const float* Wo    = (const float*)d_in[5];
    const float* bo    = (const float*)d_in[6];
    float* out = (float*)d_out;

    float* qb  = (float*)d_ws;                        // 25.6 MB (blocked)
    uint*  kvb = (uint*)(qb + (size_t)NPTS * CDIM);   // 25.6 MB (blocked)
    float* ob  = (float*)(kvb + (size_t)NPTS * CDIM); // 25.6 MB (blocked)

    const int nt = (NPTS + 63) / 64;   // 1563 blocks of 256 (64 rows x 4 quarters)
    proj_qkv<<<nt, 256, 0, stream>>>(feats, Wq, Wk, Wv, qb, kvb);
    attn_mid<<<NPTS / 4, 256, 0, stream>>>(qb, kvb, knn, ob);
    out_proj<<<nt, 256, 0, stream>>>(ob, Wo, bo, out);
}

// Round 6
// 215.926 us; speedup vs baseline: 2.3135x; 2.3135x over previous
//
#include <hip/hip_runtime.h>
#include <hip/hip_fp16.h>
#include <math.h>

#define NPTS 100000
#define CDIM 64
#define KNN  16

typedef unsigned int uint;

// DPP butterfly add: lane gets x + x[lane^mask]; CTRL is an immediate.
template <int CTRL>
__device__ __forceinline__ float dpp_add(float x) {
    int yi = __builtin_amdgcn_mov_dpp(__float_as_int(x), CTRL, 0xF, 0xF, true);
    return x + __int_as_float(yi);
}

// ---------------------------------------------------------------------------
// Kernel A: fused q/k/v projection.  Block 256 = 64 rows x 4 col-quarters.
// quarter is forced scalar via readfirstlane so all W addresses are provably
// wave-uniform -> s_load stream (scalar pipe).  Thread computes its 16 cols
// for q, k, v sequentially; feats row is re-read 8B-chunks per jo (L1-hot,
// proven compulsory-only in R4).  Outputs row-major: q fp32, kv f16-packed
// (k | v<<16) so attn gathers one dword per channel.
// ---------------------------------------------------------------------------
__global__ __launch_bounds__(256, 4) void proj_qkv(
    const float* __restrict__ feats,
    const float* __restrict__ Wq, const float* __restrict__ Wk,
    const float* __restrict__ Wv,
    float* __restrict__ q, uint* __restrict__ kv)
{
    const int t = threadIdx.x;
    const int quarter = __builtin_amdgcn_readfirstlane(t >> 6);  // scalar!
    const int c0 = quarter * 16;
    const long row = (long)blockIdx.x * 64 + (t & 63);
    const bool valid = row < NPTS;
    const long lrow = valid ? row : (NPTS - 1);
    const float4* fr = (const float4*)(feats + lrow * 64);

    float acc[16];
    uint kb[8];

    // ---- q ----
    #pragma unroll
    for (int i = 0; i < 16; ++i) acc[i] = 0.f;
    #pragma unroll 1
    for (int jo = 0; jo < 8; ++jo) {
        const float4 fa = fr[jo * 2], fb = fr[jo * 2 + 1];
        const float fch[8] = {fa.x, fa.y, fa.z, fa.w, fb.x, fb.y, fb.z, fb.w};
        #pragma unroll
        for (int ji = 0; ji < 8; ++ji) {
            const float fj = fch[ji];
            const float4* wr = (const float4*)(Wq + (size_t)(jo * 8 + ji) * 64 + c0);
            #pragma unroll
            for (int c4 = 0; c4 < 4; ++c4) {
                const float4 w = wr[c4];             // uniform -> s_load
                acc[4*c4+0] += fj * w.x; acc[4*c4+1] += fj * w.y;
                acc[4*c4+2] += fj * w.z; acc[4*c4+3] += fj * w.w;
            }
        }
    }
    if (valid) {
        float4* orow = (float4*)(q + row * 64 + c0);
        #pragma unroll
        for (int i = 0; i < 4; ++i)
            orow[i] = make_float4(acc[4*i], acc[4*i+1], acc[4*i+2], acc[4*i+3]);
    }

    // ---- k ----
    #pragma unroll
    for (int i = 0; i < 16; ++i) acc[i] = 0.f;
    #pragma unroll 1
    for (int jo = 0; jo < 8; ++jo) {
        const float4 fa = fr[jo * 2], fb = fr[jo * 2 + 1];
        const float fch[8] = {fa.x, fa.y, fa.z, fa.w, fb.x, fb.y, fb.z, fb.w};
        #pragma unroll
        for (int ji = 0; ji < 8; ++ji) {
            const float fj = fch[ji];
            const float4* wr = (const float4*)(Wk + (size_t)(jo * 8 + ji) * 64 + c0);
            #pragma unroll
            for (int c4 = 0; c4 < 4; ++c4) {
                const float4 w = wr[c4];
                acc[4*c4+0] += fj * w.x; acc[4*c4+1] += fj * w.y;
                acc[4*c4+2] += fj * w.z; acc[4*c4+3] += fj * w.w;
            }
        }
    }
    #pragma unroll
    for (int i = 0; i < 8; ++i)
        kb[i] = (uint)__half_as_ushort(__float2half(acc[i * 2]))
              | ((uint)__half_as_ushort(__float2half(acc[i * 2 + 1])) << 16);

    // ---- v + store packed kv ----
    #pragma unroll
    for (int i = 0; i < 16; ++i) acc[i] = 0.f;
    #pragma unroll 1
    for (int jo = 0; jo < 8; ++jo) {
        const float4 fa = fr[jo * 2], fb = fr[jo * 2 + 1];
        const float fch[8] = {fa.x, fa.y, fa.z, fa.w, fb.x, fb.y, fb.z, fb.w};
        #pragma unroll
        for (int ji = 0; ji < 8; ++ji) {
            const float fj = fch[ji];
            const float4* wr = (const float4*)(Wv + (size_t)(jo * 8 + ji) * 64 + c0);
            #pragma unroll
            for (int c4 = 0; c4 < 4; ++c4) {
                const float4 w = wr[c4];
                acc[4*c4+0] += fj * w.x; acc[4*c4+1] += fj * w.y;
                acc[4*c4+2] += fj * w.z; acc[4*c4+3] += fj * w.w;
            }
        }
    }
    if (valid) {
        uint4* krow = (uint4*)(kv + row * 64 + c0);
        #pragma unroll
        for (int i = 0; i < 4; ++i) {
            uint w[4];
            #pragma unroll
            for (int jj = 0; jj < 4; ++jj) {
                const int c = 4*i + jj;
                const uint kk = (c & 1) ? (kb[c >> 1] >> 16) : (kb[c >> 1] & 0xffffu);
                w[jj] = kk | ((uint)__half_as_ushort(__float2half(acc[c])) << 16);
            }
            krow[i] = make_uint4(w[0], w[1], w[2], w[3]);
        }
    }
}

// ---------------------------------------------------------------------------
// Kernel B: per-point kNN attention -> o_mid.  1 wave = 1 point, lane = c =
// h*8+d.  knn via readfirstlane -> s_load; one dword gather per neighbor
// (f16 k|v); dot over D=8 via DPP butterfly.  Zero DS-pipe ops.  (R4 form.)
// ---------------------------------------------------------------------------
__global__ __launch_bounds__(256) void attn_mid(
    const float* __restrict__ q, const uint* __restrict__ kv,
    const int* __restrict__ knn, float* __restrict__ o_mid)
{
    const int t = threadIdx.x;
    const int lane = t & 63;
    const int n = blockIdx.x * 4 + (t >> 6);
    const int ns = __builtin_amdgcn_readfirstlane(n);

    const float qv = q[(size_t)n * 64 + lane];

    const int* kr = knn + (size_t)ns * KNN;
    int idx[KNN];
    #pragma unroll
    for (int i = 0; i < KNN; ++i) idx[i] = kr[i];   // uniform -> s_load

    float sc[KNN], vr[KNN];
    #pragma unroll
    for (int i = 0; i < KNN; ++i) {
        const uint w = kv[(size_t)idx[i] * 64 + lane];
        const float2 kvf = __half22float2(*(const __half2*)&w);
        vr[i] = kvf.y;
        float p = qv * kvf.x;
        p = dpp_add<0xB1>(p);    // quad_perm xor 1
        p = dpp_add<0x4E>(p);    // quad_perm xor 2
        p = dpp_add<0x141>(p);   // row_half_mirror == xor 7
        sc[i] = p * 0.3535533905932738f;   // 1/sqrt(8)
    }

    float m = sc[0];
    #pragma unroll
    for (int i = 1; i < KNN; ++i) m = fmaxf(m, sc[i]);
    float s = 0.f;
    #pragma unroll
    for (int i = 0; i < KNN; ++i) { sc[i] = __expf(sc[i] - m); s += sc[i]; }
    const float inv = 1.f / s;

    float acc = 0.f;
    #pragma unroll
    for (int i = 0; i < KNN; ++i) acc += sc[i] * vr[i];

    o_mid[(size_t)n * 64 + lane] = acc * inv;
}

// ---------------------------------------------------------------------------
// Kernel C: out = o_mid @ Wo + bo.  Same quarter-split s_load skeleton as A.
// ---------------------------------------------------------------------------
__global__ __launch_bounds__(256, 4) void out_proj(
    const float* __restrict__ o_mid, const float* __restrict__ Wo,
    const float* __restrict__ bo, float* __restrict__ out)
{
    const int t = threadIdx.x;
    const int quarter = __builtin_amdgcn_readfirstlane(t >> 6);  // scalar!
    const int c0 = quarter * 16;
    const long row = (long)blockIdx.x * 64 + (t & 63);
    const bool valid = row < NPTS;
    const long lrow = valid ? row : (NPTS - 1);
    const float4* fr = (const float4*)(o_mid + lrow * 64);

    float acc[16];
    {
        const float4* br = (const float4*)(bo + c0);
        #pragma unroll
        for (int i = 0; i < 4; ++i) {                // uniform -> s_load
            const float4 b = br[i];
            acc[4*i+0] = b.x; acc[4*i+1] = b.y; acc[4*i+2] = b.z; acc[4*i+3] = b.w;
        }
    }
    #pragma unroll 1
    for (int jo = 0; jo < 8; ++jo) {
        const float4 fa = fr[jo * 2], fb = fr[jo * 2 + 1];
        const float fch[8] = {fa.x, fa.y, fa.z, fa.w, fb.x, fb.y, fb.z, fb.w};
        #pragma unroll
        for (int ji = 0; ji < 8; ++ji) {
            const float fj = fch[ji];
            const float4* wr = (const float4*)(Wo + (size_t)(jo * 8 + ji) * 64 + c0);
            #pragma unroll
            for (int c4 = 0; c4 < 4; ++c4) {
                const float4 w = wr[c4];
                acc[4*c4+0] += fj * w.x; acc[4*c4+1] += fj * w.y;
                acc[4*c4+2] += fj * w.z; acc[4*c4+3] += fj * w.w;
            }
        }
    }
    if (valid) {
        float4* orow = (float4*)(out + row * 64 + c0);
        #pragma unroll
        for (int i = 0; i < 4; ++i)
            orow[i] = make_float4(acc[4*i], acc[4*i+1], acc[4*i+2], acc[4*i+3]);
    }
}

extern "C" void kernel_launch(void* const* d_in, const int* in_sizes, int n_in,
                              void* d_out, int out_size, void* d_ws, size_t ws_size,
                              hipStream_t stream) {
    const float* feats = (const float*)d_in[0];
    const int*   knn   = (const int*)d_in[1];
    const float* Wq    = (const float*)d_in[2];
    const float* Wk    = (const float*)d_in[3];
    const float* Wv    = (const float*)d_in[4];
    const float* Wo    = (const float*)d_in[5];
    const float* bo    = (const float*)d_in[6];
    float* out = (float*)d_out;

    float* q     = (float*)d_ws;                          // 25.6 MB
    uint*  kvbuf = (uint*)(q + (size_t)NPTS * CDIM);      // 25.6 MB
    float* o_mid = (float*)(kvbuf + (size_t)NPTS * CDIM); // 25.6 MB

    const int nt = (NPTS + 63) / 64;   // 1563 blocks of 256 (64 rows x 4 quarters)
    proj_qkv<<<nt, 256, 0, stream>>>(feats, Wq, Wk, Wv, q, kvbuf);
    attn_mid<<<NPTS / 4, 256, 0, stream>>>(q, kvbuf, knn, o_mid);
    out_proj<<<nt, 256, 0, stream>>>(o_mid, Wo, bo, out);
}

// Round 7
// 169.291 us; speedup vs baseline: 2.9508x; 1.2755x over previous
//
#include <hip/hip_runtime.h>
#include <hip/hip_fp16.h>
#include <math.h>

#define NPTS 100000
#define CDIM 64
#define KNN  16

typedef unsigned int uint;
typedef _Float16 f16x8 __attribute__((ext_vector_type(8)));
typedef float    f32x4 __attribute__((ext_vector_type(4)));

// DPP butterfly add: lane gets x + x[lane^mask]; CTRL is an immediate.
template <int CTRL>
__device__ __forceinline__ float dpp_add(float x) {
    int yi = __builtin_amdgcn_mov_dpp(__float_as_int(x), CTRL, 0xF, 0xF, true);
    return x + __int_as_float(yi);
}

// MFMA 16x16x32 f16 fragment map (m120/m89-verified):
//   A[m][k]: m = lane&15, k = quad*8 + j   (quad = lane>>4, j = 0..7)
//   B[k][n]: n = lane&15, k = quad*8 + j
//   C/D:     col = lane&15, row = quad*4 + reg
__device__ __forceinline__ f16x8 load_bfrag(const float* W, int ks, int quad,
                                            int ct, int m) {
    const float* wp = W + (size_t)(ks * 32 + quad * 8) * 64 + ct * 16 + m;
    f16x8 b;
    #pragma unroll
    for (int j = 0; j < 8; ++j) b[j] = (_Float16)wp[j * 64];
    return b;
}

__device__ __forceinline__ f16x8 load_afrag(const float* fp, int ks, int quad) {
    const float4 x0 = *(const float4*)(fp + ks * 32 + quad * 8);
    const float4 x1 = *(const float4*)(fp + ks * 32 + quad * 8 + 4);
    f16x8 a;
    a[0] = (_Float16)x0.x; a[1] = (_Float16)x0.y;
    a[2] = (_Float16)x0.z; a[3] = (_Float16)x0.w;
    a[4] = (_Float16)x1.x; a[5] = (_Float16)x1.y;
    a[6] = (_Float16)x1.z; a[7] = (_Float16)x1.w;
    return a;
}

// ---------------------------------------------------------------------------
// Kernel A: q/k/v projection via MFMA.  One wave per 16-row tile (grid-
// stride).  All three W matrices live in the wave's VGPRs as B-fragments
// (3*4*2 = 24 f16x8 = 96 VGPRs), loaded once (L2-hot).  Per tile: 2 A-frag
// loads, 24 MFMAs, 32 dword stores.  q fp32; k,v packed f16 (k | v<<16).
// 100000 rows = 6250 tiles exactly.
// ---------------------------------------------------------------------------
__global__ __launch_bounds__(256) void proj_qkv(
    const float* __restrict__ feats,
    const float* __restrict__ Wq, const float* __restrict__ Wk,
    const float* __restrict__ Wv,
    float* __restrict__ q, uint* __restrict__ kv)
{
    const int lane = threadIdx.x & 63;
    const int m = lane & 15, quad = lane >> 4;

    f16x8 Bf[3][4][2];
    #pragma unroll
    for (int ct = 0; ct < 4; ++ct)
        #pragma unroll
        for (int ks = 0; ks < 2; ++ks) {
            Bf[0][ct][ks] = load_bfrag(Wq, ks, quad, ct, m);
            Bf[1][ct][ks] = load_bfrag(Wk, ks, quad, ct, m);
            Bf[2][ct][ks] = load_bfrag(Wv, ks, quad, ct, m);
        }

    const int wid = blockIdx.x * 4 + (threadIdx.x >> 6);
    const int nw = gridDim.x * 4;
    for (int tile = wid; tile < NPTS / 16; tile += nw) {
        const int r0 = tile * 16;
        const float* fp = feats + (size_t)(r0 + m) * 64;
        f16x8 Af0 = load_afrag(fp, 0, quad);
        f16x8 Af1 = load_afrag(fp, 1, quad);

        #pragma unroll
        for (int ct = 0; ct < 4; ++ct) {
            f32x4 aq = {0.f, 0.f, 0.f, 0.f};
            f32x4 ak = {0.f, 0.f, 0.f, 0.f};
            f32x4 av = {0.f, 0.f, 0.f, 0.f};
            aq = __builtin_amdgcn_mfma_f32_16x16x32_f16(Af0, Bf[0][ct][0], aq, 0, 0, 0);
            aq = __builtin_amdgcn_mfma_f32_16x16x32_f16(Af1, Bf[0][ct][1], aq, 0, 0, 0);
            ak = __builtin_amdgcn_mfma_f32_16x16x32_f16(Af0, Bf[1][ct][0], ak, 0, 0, 0);
            ak = __builtin_amdgcn_mfma_f32_16x16x32_f16(Af1, Bf[1][ct][1], ak, 0, 0, 0);
            av = __builtin_amdgcn_mfma_f32_16x16x32_f16(Af0, Bf[2][ct][0], av, 0, 0, 0);
            av = __builtin_amdgcn_mfma_f32_16x16x32_f16(Af1, Bf[2][ct][1], av, 0, 0, 0);

            const int col = ct * 16 + m;
            #pragma unroll
            for (int r = 0; r < 4; ++r) {
                const size_t off = (size_t)(r0 + quad * 4 + r) * 64 + col;
                q[off] = aq[r];
                kv[off] = (uint)__half_as_ushort(__float2half(ak[r]))
                        | ((uint)__half_as_ushort(__float2half(av[r])) << 16);
            }
        }
    }
}

// ---------------------------------------------------------------------------
// Kernel B: per-point kNN attention -> o_mid.  1 wave = 1 point, lane = c =
// h*8+d.  knn via readfirstlane -> s_load; one dword gather per neighbor
// (f16 k|v); dot over D=8 via DPP butterfly.  Zero DS-pipe ops.
// ---------------------------------------------------------------------------
__global__ __launch_bounds__(256) void attn_mid(
    const float* __restrict__ q, const uint* __restrict__ kv,
    const int* __restrict__ knn, float* __restrict__ o_mid)
{
    const int t = threadIdx.x;
    const int lane = t & 63;
    const int n = blockIdx.x * 4 + (t >> 6);
    const int ns = __builtin_amdgcn_readfirstlane(n);

    const float qv = q[(size_t)n * 64 + lane];

    const int* kr = knn + (size_t)ns * KNN;
    int idx[KNN];
    #pragma unroll
    for (int i = 0; i < KNN; ++i) idx[i] = kr[i];   // uniform -> s_load

    float sc[KNN], vr[KNN];
    #pragma unroll
    for (int i = 0; i < KNN; ++i) {
        const uint w = kv[(size_t)idx[i] * 64 + lane];
        const float2 kvf = __half22float2(*(const __half2*)&w);
        vr[i] = kvf.y;
        float p = qv * kvf.x;
        p = dpp_add<0xB1>(p);    // quad_perm xor 1
        p = dpp_add<0x4E>(p);    // quad_perm xor 2
        p = dpp_add<0x141>(p);   // row_half_mirror == xor 7
        sc[i] = p * 0.3535533905932738f;   // 1/sqrt(8)
    }

    float m = sc[0];
    #pragma unroll
    for (int i = 1; i < KNN; ++i) m = fmaxf(m, sc[i]);
    float s = 0.f;
    #pragma unroll
    for (int i = 0; i < KNN; ++i) { sc[i] = __expf(sc[i] - m); s += sc[i]; }
    const float inv = 1.f / s;

    float acc = 0.f;
    #pragma unroll
    for (int i = 0; i < KNN; ++i) acc += sc[i] * vr[i];

    o_mid[(size_t)n * 64 + lane] = acc * inv;
}

// ---------------------------------------------------------------------------
// Kernel C: out = o_mid @ Wo + bo via MFMA.  Same skeleton as A, 1 matrix.
// ---------------------------------------------------------------------------
__global__ __launch_bounds__(256) void out_proj(
    const float* __restrict__ o_mid, const float* __restrict__ Wo,
    const float* __restrict__ bo, float* __restrict__ out)
{
    const int lane = threadIdx.x & 63;
    const int m = lane & 15, quad = lane >> 4;

    f16x8 Bf[4][2];
    float bias[4];
    #pragma unroll
    for (int ct = 0; ct < 4; ++ct) {
        bias[ct] = bo[ct * 16 + m];
        #pragma unroll
        for (int ks = 0; ks < 2; ++ks)
            Bf[ct][ks] = load_bfrag(Wo, ks, quad, ct, m);
    }

    const int wid = blockIdx.x * 4 + (threadIdx.x >> 6);
    const int nw = gridDim.x * 4;
    for (int tile = wid; tile < NPTS / 16; tile += nw) {
        const int r0 = tile * 16;
        const float* fp = o_mid + (size_t)(r0 + m) * 64;
        f16x8 Af0 = load_afrag(fp, 0, quad);
        f16x8 Af1 = load_afrag(fp, 1, quad);

        #pragma unroll
        for (int ct = 0; ct < 4; ++ct) {
            f32x4 ac = {0.f, 0.f, 0.f, 0.f};
            ac = __builtin_amdgcn_mfma_f32_16x16x32_f16(Af0, Bf[ct][0], ac, 0, 0, 0);
            ac = __builtin_amdgcn_mfma_f32_16x16x32_f16(Af1, Bf[ct][1], ac, 0, 0, 0);

            const int col = ct * 16 + m;
            #pragma unroll
            for (int r = 0; r < 4; ++r)
                out[(size_t)(r0 + quad * 4 + r) * 64 + col] = ac[r] + bias[ct];
        }
    }
}

extern "C" void kernel_launch(void* const* d_in, const int* in_sizes, int n_in,
                              void* d_out, int out_size, void* d_ws, size_t ws_size,
                              hipStream_t stream) {
    const float* feats = (const float*)d_in[0];
    const int*   knn   = (const int*)d_in[1];
    const float* Wq    = (const float*)d_in[2];
    const float* Wk    = (const float*)d_in[3];
    const float* Wv    = (const float*)d_in[4];
    const float* Wo    = (const float*)d_in[5];
    const float* bo    = (const float*)d_in[6];
    float* out = (float*)d_out;

    float* q     = (float*)d_ws;                          // 25.6 MB
    uint*  kvbuf = (uint*)(q + (size_t)NPTS * CDIM);      // 25.6 MB
    float* o_mid = (float*)(kvbuf + (size_t)NPTS * CDIM); // 25.6 MB

    proj_qkv<<<512, 256, 0, stream>>>(feats, Wq, Wk, Wv, q, kvbuf);
    attn_mid<<<NPTS / 4, 256, 0, stream>>>(q, kvbuf, knn, o_mid);
    out_proj<<<512, 256, 0, stream>>>(o_mid, Wo, bo, out);
}

// Round 8
// 158.199 us; speedup vs baseline: 3.1577x; 1.0701x over previous
//
#include <hip/hip_runtime.h>
#include <hip/hip_fp16.h>
#include <math.h>

#define NPTS 100000
#define CDIM 64
#define KNN  16

typedef unsigned int uint;
typedef _Float16 f16x8 __attribute__((ext_vector_type(8)));
typedef float    f32x4 __attribute__((ext_vector_type(4)));

// DPP butterfly add: lane gets x + x[lane^mask]; CTRL is an immediate.
template <int CTRL>
__device__ __forceinline__ float dpp_add(float x) {
    int yi = __builtin_amdgcn_mov_dpp(__float_as_int(x), CTRL, 0xF, 0xF, true);
    return x + __int_as_float(yi);
}

// MFMA 16x16x32 f16 fragment map:
//   A[m][k]: m = lane&15, k = quad*8 + j
//   B[k][n]: n = lane&15, k = quad*8 + j
//   C/D:     col = lane&15, row = quad*4 + reg
// Fragment buffer: frag[mat][ct][ks][lane] = f16x8, mat 0..3 = Wq,Wk,Wv,Wo.

// ---------------------------------------------------------------------------
// Kernel 0: pre-convert W matrices into B-fragment order (f16).  2048 lane-
// fragments x 8 elements; one block.
// ---------------------------------------------------------------------------
__global__ __launch_bounds__(256) void pack_w(
    const float* __restrict__ Wq, const float* __restrict__ Wk,
    const float* __restrict__ Wv, const float* __restrict__ Wo,
    __half* __restrict__ frag)
{
    const float* Ws[4] = {Wq, Wk, Wv, Wo};
    f16x8* fp = (f16x8*)frag;
    for (int e = threadIdx.x; e < 2048; e += 256) {
        const int lane = e & 63;
        const int ks   = (e >> 6) & 1;
        const int ct   = (e >> 7) & 3;
        const int mat  = e >> 9;
        const int m = lane & 15, quad = lane >> 4;
        const float* W = Ws[mat];
        f16x8 b;
        #pragma unroll
        for (int j = 0; j < 8; ++j)
            b[j] = (_Float16)W[(size_t)(ks * 32 + quad * 8 + j) * 64 + ct * 16 + m];
        fp[e] = b;
    }
}

__device__ __forceinline__ f16x8 load_afrag(const float* fp, int ks, int quad) {
    const float4 x0 = *(const float4*)(fp + ks * 32 + quad * 8);
    const float4 x1 = *(const float4*)(fp + ks * 32 + quad * 8 + 4);
    f16x8 a;
    a[0] = (_Float16)x0.x; a[1] = (_Float16)x0.y;
    a[2] = (_Float16)x0.z; a[3] = (_Float16)x0.w;
    a[4] = (_Float16)x1.x; a[5] = (_Float16)x1.y;
    a[6] = (_Float16)x1.z; a[7] = (_Float16)x1.w;
    return a;
}

// ---------------------------------------------------------------------------
// Kernel A: q/k/v projection via MFMA.  One wave per 16-row tile (6250 tiles,
// 1563 blocks x 4 waves).  B-fragments: 24 coalesced 16B loads from the
// pre-packed buffer (no gathers, no cvts).  q stored f16; k,v packed f16
// (k | v<<16).
// ---------------------------------------------------------------------------
__global__ __launch_bounds__(256) void proj_qkv(
    const float* __restrict__ feats, const __half* __restrict__ frag,
    __half* __restrict__ q, uint* __restrict__ kv)
{
    const int wid = blockIdx.x * 4 + (threadIdx.x >> 6);
    if (wid >= NPTS / 16) return;
    const int lane = threadIdx.x & 63;
    const int m = lane & 15, quad = lane >> 4;

    const f16x8* fp = (const f16x8*)frag;
    f16x8 Bf[3][4][2];
    #pragma unroll
    for (int mat = 0; mat < 3; ++mat)
        #pragma unroll
        for (int ct = 0; ct < 4; ++ct)
            #pragma unroll
            for (int ks = 0; ks < 2; ++ks)
                Bf[mat][ct][ks] = fp[((mat * 4 + ct) * 2 + ks) * 64 + lane];

    const int r0 = wid * 16;
    const float* ap = feats + (size_t)(r0 + m) * 64;
    const f16x8 Af0 = load_afrag(ap, 0, quad);
    const f16x8 Af1 = load_afrag(ap, 1, quad);

    #pragma unroll
    for (int ct = 0; ct < 4; ++ct) {
        f32x4 aq = {0.f, 0.f, 0.f, 0.f};
        f32x4 ak = {0.f, 0.f, 0.f, 0.f};
        f32x4 av = {0.f, 0.f, 0.f, 0.f};
        aq = __builtin_amdgcn_mfma_f32_16x16x32_f16(Af0, Bf[0][ct][0], aq, 0, 0, 0);
        aq = __builtin_amdgcn_mfma_f32_16x16x32_f16(Af1, Bf[0][ct][1], aq, 0, 0, 0);
        ak = __builtin_amdgcn_mfma_f32_16x16x32_f16(Af0, Bf[1][ct][0], ak, 0, 0, 0);
        ak = __builtin_amdgcn_mfma_f32_16x16x32_f16(Af1, Bf[1][ct][1], ak, 0, 0, 0);
        av = __builtin_amdgcn_mfma_f32_16x16x32_f16(Af0, Bf[2][ct][0], av, 0, 0, 0);
        av = __builtin_amdgcn_mfma_f32_16x16x32_f16(Af1, Bf[2][ct][1], av, 0, 0, 0);

        const int col = ct * 16 + m;
        #pragma unroll
        for (int r = 0; r < 4; ++r) {
            const size_t off = (size_t)(r0 + quad * 4 + r) * 64 + col;
            q[off] = __float2half(aq[r]);
            kv[off] = (uint)__half_as_ushort(__float2half(ak[r]))
                    | ((uint)__half_as_ushort(__float2half(av[r])) << 16);
        }
    }
}

// ---------------------------------------------------------------------------
// Kernel B: fused kNN attention + output projection.  Block = 16 points.
// Phase 1: wave w computes attention for its 4 points (lane = channel,
// dword kv gather, DPP dot, softmax) and writes o rows to padded LDS.
// Phase 2: wave w computes col-quadrant ct=w of o @ Wo + bo via 2 MFMAs
// (A from LDS, B from the pre-packed Wo fragments) and stores out.
// ---------------------------------------------------------------------------
__global__ __launch_bounds__(256) void attn_out(
    const __half* __restrict__ q, const uint* __restrict__ kv,
    const int* __restrict__ knn, const __half* __restrict__ frag,
    const float* __restrict__ bo, float* __restrict__ out)
{
    __shared__ float sO[16][68];   // +4 pad: 2-way banks on both phases
    const int t = threadIdx.x;
    const int lane = t & 63;
    const int w = t >> 6;
    const int m = lane & 15, quad = lane >> 4;

    // Wo fragments + bias for this wave's quadrant (ct = w).
    const f16x8* fpb = (const f16x8*)frag;
    const f16x8 Wf0 = fpb[((3 * 4 + w) * 2 + 0) * 64 + lane];
    const f16x8 Wf1 = fpb[((3 * 4 + w) * 2 + 1) * 64 + lane];
    const float bias = bo[w * 16 + m];

    const int n0 = blockIdx.x * 16;

    #pragma unroll 1
    for (int p = 0; p < 4; ++p) {
        const int n = n0 + w * 4 + p;
        const int ns = __builtin_amdgcn_readfirstlane(n);

        const float qv = __half2float(q[(size_t)n * 64 + lane]);

        const int* kr = knn + (size_t)ns * KNN;
        int idx[KNN];
        #pragma unroll
        for (int i = 0; i < KNN; ++i) idx[i] = kr[i];   // uniform -> s_load

        float sc[KNN], vr[KNN];
        #pragma unroll
        for (int i = 0; i < KNN; ++i) {
            const uint wv = kv[(size_t)idx[i] * 64 + lane];
            const float2 kvf = __half22float2(*(const __half2*)&wv);
            vr[i] = kvf.y;
            float pr = qv * kvf.x;
            pr = dpp_add<0xB1>(pr);    // xor 1
            pr = dpp_add<0x4E>(pr);    // xor 2
            pr = dpp_add<0x141>(pr);   // xor 7 (row_half_mirror)
            sc[i] = pr * 0.3535533905932738f;   // 1/sqrt(8)
        }

        float mx = sc[0];
        #pragma unroll
        for (int i = 1; i < KNN; ++i) mx = fmaxf(mx, sc[i]);
        float s = 0.f;
        #pragma unroll
        for (int i = 0; i < KNN; ++i) { sc[i] = __expf(sc[i] - mx); s += sc[i]; }
        const float inv = 1.f / s;

        float acc = 0.f;
        #pragma unroll
        for (int i = 0; i < KNN; ++i) acc += sc[i] * vr[i];

        sO[w * 4 + p][lane] = acc * inv;
    }
    __syncthreads();

    // Phase 2: ct = w quadrant of the 16x64 output tile.
    const float* ap = &sO[m][0];
    f16x8 Af0, Af1;
    {
        const float4 x0 = *(const float4*)(ap + quad * 8);
        const float4 x1 = *(const float4*)(ap + quad * 8 + 4);
        Af0[0] = (_Float16)x0.x; Af0[1] = (_Float16)x0.y;
        Af0[2] = (_Float16)x0.z; Af0[3] = (_Float16)x0.w;
        Af0[4] = (_Float16)x1.x; Af0[5] = (_Float16)x1.y;
        Af0[6] = (_Float16)x1.z; Af0[7] = (_Float16)x1.w;
        const float4 y0 = *(const float4*)(ap + 32 + quad * 8);
        const float4 y1 = *(const float4*)(ap + 32 + quad * 8 + 4);
        Af1[0] = (_Float16)y0.x; Af1[1] = (_Float16)y0.y;
        Af1[2] = (_Float16)y0.z; Af1[3] = (_Float16)y0.w;
        Af1[4] = (_Float16)y1.x; Af1[5] = (_Float16)y1.y;
        Af1[6] = (_Float16)y1.z; Af1[7] = (_Float16)y1.w;
    }

    f32x4 ac = {0.f, 0.f, 0.f, 0.f};
    ac = __builtin_amdgcn_mfma_f32_16x16x32_f16(Af0, Wf0, ac, 0, 0, 0);
    ac = __builtin_amdgcn_mfma_f32_16x16x32_f16(Af1, Wf1, ac, 0, 0, 0);

    const int col = w * 16 + m;
    #pragma unroll
    for (int r = 0; r < 4; ++r)
        out[(size_t)(n0 + quad * 4 + r) * 64 + col] = ac[r] + bias;
}

extern "C" void kernel_launch(void* const* d_in, const int* in_sizes, int n_in,
                              void* d_out, int out_size, void* d_ws, size_t ws_size,
                              hipStream_t stream) {
    const float* feats = (const float*)d_in[0];
    const int*   knn   = (const int*)d_in[1];
    const float* Wq    = (const float*)d_in[2];
    const float* Wk    = (const float*)d_in[3];
    const float* Wv    = (const float*)d_in[4];
    const float* Wo    = (const float*)d_in[5];
    const float* bo    = (const float*)d_in[6];
    float* out = (float*)d_out;

    __half* frag = (__half*)d_ws;                                  // 32 KB
    __half* q_h  = (__half*)((char*)d_ws + 32768);                 // 12.8 MB
    uint*   kvb  = (uint*)((char*)d_ws + 32768 +
                           (size_t)NPTS * CDIM * sizeof(__half));  // 25.6 MB

    pack_w<<<1, 256, 0, stream>>>(Wq, Wk, Wv, Wo, frag);
    proj_qkv<<<(NPTS / 16 + 3) / 4, 256, 0, stream>>>(feats, frag, q_h, kvb);
    attn_out<<<NPTS / 16, 256, 0, stream>>>(q_h, kvb, knn, frag, bo, out);
}